// Round 7
// baseline (926.500 us; speedup 1.0000x reference)
//
#include <hip/hip_runtime.h>
#include <hip/hip_bf16.h>

#define NN 50000
#define EE 640000
#define FF 128
#define HH 128

typedef unsigned short ushort_t;
typedef unsigned int   uint_t;
using f32x4  = __attribute__((ext_vector_type(4))) float;
using bf16x8 = __attribute__((ext_vector_type(8))) __bf16;
using u16x8  = __attribute__((ext_vector_type(8))) unsigned short;
using u16x4  = __attribute__((ext_vector_type(4))) unsigned short;

__device__ __forceinline__ ushort_t f2bf(float f) {
    union { float f; unsigned int i; } v; v.f = f;
    unsigned int r = v.i + 0x7fffu + ((v.i >> 16) & 1u);
    return (ushort_t)(r >> 16);
}
__device__ __forceinline__ float fsilu(float x) { return x / (1.f + __expf(-x)); }
__device__ __forceinline__ float fsig(float x)  { return 1.f / (1.f + __expf(-x)); }

__device__ __forceinline__ u16x8 cvt8(const float* p) {
    float4 a0 = *reinterpret_cast<const float4*>(p);
    float4 a1 = *reinterpret_cast<const float4*>(p + 4);
    u16x8 v;
    v[0] = f2bf(a0.x); v[1] = f2bf(a0.y); v[2] = f2bf(a0.z); v[3] = f2bf(a0.w);
    v[4] = f2bf(a1.x); v[5] = f2bf(a1.y); v[6] = f2bf(a1.z); v[7] = f2bf(a1.w);
    return v;
}

// 8B-aligned LDS helpers (strides are 8B- but not 16B-aligned)
__device__ __forceinline__ void st8(ushort_t* p, u16x8 v) {
    union { u16x8 v8; u16x4 h[2]; } u; u.v8 = v;
    *reinterpret_cast<u16x4*>(p)     = u.h[0];
    *reinterpret_cast<u16x4*>(p + 4) = u.h[1];
}
__device__ __forceinline__ bf16x8 ld8(const ushort_t* p) {
    union { u16x4 h[2]; bf16x8 v; } u;
    u.h[0] = *reinterpret_cast<const u16x4*>(p);
    u.h[1] = *reinterpret_cast<const u16x4*>(p + 4);
    return u.v;
}

// ---------------------------------------------------------------------------
// prep: h f32->bf16  +  degree histogram (fused)
// ---------------------------------------------------------------------------
__global__ void prep_kernel(const float* __restrict__ h, ushort_t* __restrict__ hbf,
                            const int* __restrict__ eidx, int* __restrict__ deg)
{
    const int t = blockIdx.x * 256 + threadIdx.x;
    if (t * 8 < NN * 128) {
        u16x8 v = cvt8(h + (size_t)t * 8);
        *reinterpret_cast<u16x8*>(hbf + (size_t)t * 8) = v;
    }
    if (t < EE) atomicAdd(&deg[eidx[t]], 1);
}

__global__ void scan_kernel(const int* __restrict__ deg, int* __restrict__ row_ptr,
                            int* __restrict__ cursor)
{
    __shared__ int sdata[1024];
    const int t = threadIdx.x;
    const int chunk = (NN + 1023) / 1024;
    const int start = t * chunk;
    const int end   = min(start + chunk, NN);
    int s = 0;
    for (int i = start; i < end; ++i) s += deg[i];
    sdata[t] = s;
    __syncthreads();
    for (int off = 1; off < 1024; off <<= 1) {
        int v = (t >= off) ? sdata[t - off] : 0;
        __syncthreads();
        sdata[t] += v;
        __syncthreads();
    }
    int ox = sdata[t] - s;
    for (int i = start; i < end; ++i) {
        row_ptr[i] = ox; cursor[i] = ox; ox += deg[i];
    }
    if (t == 1023) row_ptr[NN] = sdata[1023];
}

__global__ void scatter_kernel(const int* __restrict__ eidx, int* __restrict__ cursor,
                               int* __restrict__ edge_list)
{
    const int e = blockIdx.x * 256 + threadIdx.x;
    if (e < EE) {
        const int r = eidx[e];
        const int p = atomicAdd(&cursor[r], 1);
        edge_list[p] = e;
    }
}

// ---------------------------------------------------------------------------
// Edge kernel: sequential 64-edge tiles, no atomics, 4 barriers.
// LDS = A(64x292) + M1(64x132) = 54,272B -> 3 blocks/CU.
// M2 aliases the dead A region after layer1. PD (pos diffs) lives in the
// staging lanes' REGISTERS (staging lane 16lg+4rr and gate consumer are in
// the same wave) -> fetched via __shfl in the gate phase.
// ---------------------------------------------------------------------------
#define A_STR 292
#define M_STR 132

__global__ __launch_bounds__(256, 3) void egcl_edge_kernel(
    const ushort_t* __restrict__ hbf, const float* __restrict__ pos,
    const int* __restrict__ eidx, const float* __restrict__ eattr,
    const float* __restrict__ w1, const float* __restrict__ b1,
    const float* __restrict__ w2, const float* __restrict__ b2,
    const float* __restrict__ aW, const float* __restrict__ ab,
    const float* __restrict__ pW2,
    float* __restrict__ m_out, float* __restrict__ trans_out)
{
    __shared__ __align__(16) ushort_t A_sh[64 * A_STR];   // 37,376 B
    __shared__ __align__(16) ushort_t M1_sh[64 * M_STR];  // 16,896 B

    ushort_t* M2_sh = A_sh;                               // [64][132], dead-A alias

    const int tid  = threadIdx.x;
    const int lane = tid & 63;
    const int w    = tid >> 6;
    const int l15  = lane & 15;
    const int lg   = lane >> 4;

    // ---- weights in registers (per wave: cols 32w..32w+31) ----
    bf16x8 B1[9][2];
    bf16x8 B2[4][2];
    bf16x8 Bg[4];
    float b1c[2], b2c[2];
    const float abv = ab[0];
#pragma unroll
    for (int nt = 0; nt < 2; ++nt) {
        const int colg = 32 * w + 16 * nt + l15;
        b1c[nt] = b1[colg];
        b2c[nt] = b2[colg];
#pragma unroll
        for (int ks = 0; ks < 9; ++ks) {
            u16x8 v;
#pragma unroll
            for (int j = 0; j < 8; ++j) {
                const int k = 32 * ks + 8 * lg + j;
                v[j] = (k < 265) ? f2bf(w1[k * 128 + colg]) : (ushort_t)0;
            }
            B1[ks][nt] = __builtin_bit_cast(bf16x8, v);
        }
#pragma unroll
        for (int ks = 0; ks < 4; ++ks) {
            u16x8 v;
#pragma unroll
            for (int j = 0; j < 8; ++j) {
                const int k = 32 * ks + 8 * lg + j;
                v[j] = f2bf(w2[k * 128 + colg]);
            }
            B2[ks][nt] = __builtin_bit_cast(bf16x8, v);
        }
    }
#pragma unroll
    for (int ks = 0; ks < 4; ++ks) {
        u16x8 v;
#pragma unroll
        for (int j = 0; j < 8; ++j) {
            const int k = 32 * ks + 8 * lg + j;
            v[j] = (l15 == 0) ? f2bf(aW[k]) : (l15 == 1 ? f2bf(pW2[k]) : (ushort_t)0);
        }
        Bg[ks] = __builtin_bit_cast(bf16x8, v);
    }

    const int ei = tid >> 2;   // edge slot 0..63
    const int et = tid & 3;    // 4 threads/slot, 32 bf16 each per row

    for (int tile = blockIdx.x; tile < EE / 64; tile += gridDim.x) {
        // ---- stage (pd kept in registers on et==0 lanes) ----
        float pdx = 0.f, pdy = 0.f, pdz = 0.f;
        {
            const int e = tile * 64 + ei;
            const int r = eidx[e];
            const int c = eidx[EE + e];
            const ushort_t* hr = hbf + (size_t)r * 128 + et * 32;
            const ushort_t* hc = hbf + (size_t)c * 128 + et * 32;
#pragma unroll
            for (int q = 0; q < 4; ++q) {
                st8(&A_sh[ei * A_STR + et * 32 + q * 8],
                    *reinterpret_cast<const u16x8*>(hr + q * 8));
                st8(&A_sh[ei * A_STR + 128 + et * 32 + q * 8],
                    *reinterpret_cast<const u16x8*>(hc + q * 8));
            }
            if (et == 0) {
                pdx = pos[r * 3 + 0] - pos[c * 3 + 0];
                pdy = pos[r * 3 + 1] - pos[c * 3 + 1];
                pdz = pos[r * 3 + 2] - pos[c * 3 + 2];
                const float ds = pdx * pdx + pdy * pdy + pdz * pdz;
                const float4 ea0 = *reinterpret_cast<const float4*>(eattr + (size_t)e * 8);
                const float4 ea1 = *reinterpret_cast<const float4*>(eattr + (size_t)e * 8 + 4);
                u16x8 v0;
                v0[0] = f2bf(ds);
                v0[1] = f2bf(ea0.x); v0[2] = f2bf(ea0.y); v0[3] = f2bf(ea0.z);
                v0[4] = f2bf(ea0.w); v0[5] = f2bf(ea1.x); v0[6] = f2bf(ea1.y);
                v0[7] = f2bf(ea1.z);
                st8(&A_sh[ei * A_STR + 256], v0);
                u16x8 v1 = {0, 0, 0, 0, 0, 0, 0, 0};
                v1[0] = f2bf(ea1.w);
                st8(&A_sh[ei * A_STR + 264], v1);
                u16x8 z = {0, 0, 0, 0, 0, 0, 0, 0};
                st8(&A_sh[ei * A_STR + 272], z);
                st8(&A_sh[ei * A_STR + 280], z);
            }
        }
        __syncthreads();                       // B1: A ready

        // ---- layer 1 ----
#pragma unroll
        for (int s = 0; s < 4; ++s) {
            f32x4 a0 = {0.f, 0.f, 0.f, 0.f};
            f32x4 a1 = {0.f, 0.f, 0.f, 0.f};
#pragma unroll
            for (int ks = 0; ks < 9; ++ks) {
                bf16x8 a = ld8(&A_sh[(16 * s + l15) * A_STR + ks * 32 + lg * 8]);
                a0 = __builtin_amdgcn_mfma_f32_16x16x32_bf16(a, B1[ks][0], a0, 0, 0, 0);
                a1 = __builtin_amdgcn_mfma_f32_16x16x32_bf16(a, B1[ks][1], a1, 0, 0, 0);
            }
#pragma unroll
            for (int nt = 0; nt < 2; ++nt) {
#pragma unroll
                for (int rr = 0; rr < 4; ++rr) {
                    const float x = (nt == 0 ? a0[rr] : a1[rr]) + b1c[nt];
                    const int edge = 16 * s + 4 * lg + rr;
                    const int colg = 32 * w + 16 * nt + l15;
                    M1_sh[edge * M_STR + colg] = f2bf(fsilu(x));
                }
            }
        }
        __syncthreads();                       // B2: M1 ready, A dead

        // ---- layer 2 (writes M2 alias in dead A region) ----
        float m2v[4][2][4];
#pragma unroll
        for (int s = 0; s < 4; ++s) {
            f32x4 a0 = {0.f, 0.f, 0.f, 0.f};
            f32x4 a1 = {0.f, 0.f, 0.f, 0.f};
#pragma unroll
            for (int ks = 0; ks < 4; ++ks) {
                bf16x8 a = ld8(&M1_sh[(16 * s + l15) * M_STR + ks * 32 + lg * 8]);
                a0 = __builtin_amdgcn_mfma_f32_16x16x32_bf16(a, B2[ks][0], a0, 0, 0, 0);
                a1 = __builtin_amdgcn_mfma_f32_16x16x32_bf16(a, B2[ks][1], a1, 0, 0, 0);
            }
#pragma unroll
            for (int nt = 0; nt < 2; ++nt) {
#pragma unroll
                for (int rr = 0; rr < 4; ++rr) {
                    const float x = (nt == 0 ? a0[rr] : a1[rr]) + b2c[nt];
                    const float sv = fsilu(x);
                    m2v[s][nt][rr] = sv;
                    const int edge = 16 * s + 4 * lg + rr;
                    const int colg = 32 * w + 16 * nt + l15;
                    M2_sh[edge * M_STR + colg] = f2bf(sv);
                }
            }
        }
        __syncthreads();                       // B3: M2 ready

        // ---- gate (all subtiles per wave) + trans write (own subtile) ----
        float gq[4][4];
#pragma unroll
        for (int s = 0; s < 4; ++s) {
            f32x4 ga = {0.f, 0.f, 0.f, 0.f};
#pragma unroll
            for (int ks = 0; ks < 4; ++ks) {
                bf16x8 a = ld8(&M2_sh[(16 * s + l15) * M_STR + ks * 32 + lg * 8]);
                ga = __builtin_amdgcn_mfma_f32_16x16x32_bf16(a, Bg[ks], ga, 0, 0, 0);
            }
#pragma unroll
            for (int rr = 0; rr < 4; ++rr) {
                const float sa = __shfl(ga[rr], lane & 48);
                gq[s][rr] = fsig(sa + abv);
                if (s == w) {
                    const float sp = __shfl(ga[rr], (lane & 48) + 1);
                    // PD of edge 16w+4lg+rr lives on lane 16lg+4rr (same wave)
                    const float px = __shfl(pdx, 16 * lg + 4 * rr);
                    const float py = __shfl(pdy, 16 * lg + 4 * rr);
                    const float pz = __shfl(pdz, 16 * lg + 4 * rr);
                    if (l15 == 0) {
                        const int edge = 16 * w + 4 * lg + rr;
                        const float t = gq[s][rr] * sp;
                        const size_t e = (size_t)tile * 64 + edge;
                        trans_out[e * 3 + 0] = px * t;
                        trans_out[e * 3 + 1] = py * t;
                        trans_out[e * 3 + 2] = pz * t;
                    }
                }
            }
        }

        // ---- gated m write (sequential rows) ----
#pragma unroll
        for (int s = 0; s < 4; ++s) {
#pragma unroll
            for (int nt = 0; nt < 2; ++nt) {
#pragma unroll
                for (int rr = 0; rr < 4; ++rr) {
                    const int edge = 16 * s + 4 * lg + rr;
                    const int colg = 32 * w + 16 * nt + l15;
                    const size_t e = (size_t)tile * 64 + edge;
                    m_out[e * 128 + colg] = m2v[s][nt][rr] * gq[s][rr];
                }
            }
        }
        __syncthreads();                       // B4: protect A/M2 for next tile
    }
}

// ---------------------------------------------------------------------------
// Gather-aggregate: one wave per node. agg (bf16) + pos update.
// ---------------------------------------------------------------------------
__global__ __launch_bounds__(256) void gather_agg_kernel(
    const float* __restrict__ m, const float* __restrict__ trans,
    const int* __restrict__ row_ptr, const int* __restrict__ edge_list,
    const float* __restrict__ pos,
    ushort_t* __restrict__ agg_bf, float* __restrict__ pos_out)
{
    const int nid = (blockIdx.x * 256 + threadIdx.x) >> 6;
    if (nid >= NN) return;
    const int lane = threadIdx.x & 63;
    const int b  = row_ptr[nid];
    const int en = row_ptr[nid + 1];

    float a0 = 0.f, a1 = 0.f, tc = 0.f;
    int j = b;
    for (; j + 4 <= en; j += 4) {
        const int e0 = edge_list[j],     e1 = edge_list[j + 1];
        const int e2 = edge_list[j + 2], e3 = edge_list[j + 3];
        const float2 v0 = *reinterpret_cast<const float2*>(m + (size_t)e0 * 128 + 2 * lane);
        const float2 v1 = *reinterpret_cast<const float2*>(m + (size_t)e1 * 128 + 2 * lane);
        const float2 v2 = *reinterpret_cast<const float2*>(m + (size_t)e2 * 128 + 2 * lane);
        const float2 v3 = *reinterpret_cast<const float2*>(m + (size_t)e3 * 128 + 2 * lane);
        a0 += v0.x + v1.x + v2.x + v3.x;
        a1 += v0.y + v1.y + v2.y + v3.y;
        if (lane < 3)
            tc += trans[(size_t)e0 * 3 + lane] + trans[(size_t)e1 * 3 + lane]
                + trans[(size_t)e2 * 3 + lane] + trans[(size_t)e3 * 3 + lane];
    }
    for (; j < en; ++j) {
        const int e0 = edge_list[j];
        const float2 v0 = *reinterpret_cast<const float2*>(m + (size_t)e0 * 128 + 2 * lane);
        a0 += v0.x; a1 += v0.y;
        if (lane < 3) tc += trans[(size_t)e0 * 3 + lane];
    }

    const uint_t pk = (uint_t)f2bf(a0) | ((uint_t)f2bf(a1) << 16);
    reinterpret_cast<uint_t*>(agg_bf)[(size_t)nid * 64 + lane] = pk;
    if (lane < 3) {
        const float c = fmaxf((float)(en - b), 1.f);
        pos_out[(size_t)nid * 3 + lane] = pos[(size_t)nid * 3 + lane] + tc / c;
    }
}

// ---------------------------------------------------------------------------
// Node MLP: h_new = silu([hbf|agg_bf]@nW1+nb1)@nW2+nb2+h  (pure streaming)
// ---------------------------------------------------------------------------
__global__ __launch_bounds__(256, 4) void egcl_node_kernel(
    const ushort_t* __restrict__ hbf, const float* __restrict__ h,
    const ushort_t* __restrict__ agg_bf,
    const float* __restrict__ w1, const float* __restrict__ b1,
    const float* __restrict__ w2, const float* __restrict__ b2,
    float* __restrict__ hn_out)
{
    __shared__ __align__(16) ushort_t A_sh[16 * 264];
    __shared__ __align__(16) ushort_t M1_sh[16 * 136];

    const int tid  = threadIdx.x;
    const int lane = tid & 63;
    const int w    = tid >> 6;
    const int l15  = lane & 15;
    const int lg   = lane >> 4;

    bf16x8 B1[8][2];
    bf16x8 B2[4][2];
    float b1c[2], b2c[2];
#pragma unroll
    for (int nt = 0; nt < 2; ++nt) {
        const int colg = 32 * w + 16 * nt + l15;
        b1c[nt] = b1[colg];
        b2c[nt] = b2[colg];
#pragma unroll
        for (int ks = 0; ks < 8; ++ks) {
            u16x8 v;
#pragma unroll
            for (int j = 0; j < 8; ++j) {
                const int k = 32 * ks + 8 * lg + j;
                v[j] = f2bf(w1[k * 128 + colg]);
            }
            B1[ks][nt] = __builtin_bit_cast(bf16x8, v);
        }
#pragma unroll
        for (int ks = 0; ks < 4; ++ks) {
            u16x8 v;
#pragma unroll
            for (int j = 0; j < 8; ++j) {
                const int k = 32 * ks + 8 * lg + j;
                v[j] = f2bf(w2[k * 128 + colg]);
            }
            B2[ks][nt] = __builtin_bit_cast(bf16x8, v);
        }
    }

    const int ni = tid >> 4;
    const int nt16 = tid & 15;

    for (int tile = blockIdx.x; tile < NN / 16; tile += gridDim.x) {
        __syncthreads();
        const int base = tile * 16;
        {
            const size_t n = (size_t)base + ni;
            *reinterpret_cast<u16x8*>(&A_sh[ni * 264 + nt16 * 8]) =
                *reinterpret_cast<const u16x8*>(hbf + n * 128 + nt16 * 8);
            *reinterpret_cast<u16x8*>(&A_sh[ni * 264 + 128 + nt16 * 8]) =
                *reinterpret_cast<const u16x8*>(agg_bf + n * 128 + nt16 * 8);
        }
        __syncthreads();

        f32x4 acc10 = {0.f, 0.f, 0.f, 0.f};
        f32x4 acc11 = {0.f, 0.f, 0.f, 0.f};
#pragma unroll
        for (int ks = 0; ks < 8; ++ks) {
            bf16x8 a = *reinterpret_cast<const bf16x8*>(&A_sh[l15 * 264 + ks * 32 + lg * 8]);
            acc10 = __builtin_amdgcn_mfma_f32_16x16x32_bf16(a, B1[ks][0], acc10, 0, 0, 0);
            acc11 = __builtin_amdgcn_mfma_f32_16x16x32_bf16(a, B1[ks][1], acc11, 0, 0, 0);
        }
#pragma unroll
        for (int nt = 0; nt < 2; ++nt) {
#pragma unroll
            for (int r = 0; r < 4; ++r) {
                const float x = (nt == 0 ? acc10[r] : acc11[r]) + b1c[nt];
                const int nl = 4 * lg + r;
                const int colg = 32 * w + 16 * nt + l15;
                M1_sh[nl * 136 + colg] = f2bf(fsilu(x));
            }
        }
        __syncthreads();

        f32x4 acc20 = {0.f, 0.f, 0.f, 0.f};
        f32x4 acc21 = {0.f, 0.f, 0.f, 0.f};
#pragma unroll
        for (int ks = 0; ks < 4; ++ks) {
            bf16x8 a = *reinterpret_cast<const bf16x8*>(&M1_sh[l15 * 136 + ks * 32 + lg * 8]);
            acc20 = __builtin_amdgcn_mfma_f32_16x16x32_bf16(a, B2[ks][0], acc20, 0, 0, 0);
            acc21 = __builtin_amdgcn_mfma_f32_16x16x32_bf16(a, B2[ks][1], acc21, 0, 0, 0);
        }
#pragma unroll
        for (int nt = 0; nt < 2; ++nt) {
#pragma unroll
            for (int r = 0; r < 4; ++r) {
                const int nl = 4 * lg + r;
                const int colg = 32 * w + 16 * nt + l15;
                const size_t n = (size_t)base + nl;
                const float hres = h[n * 128 + colg];
                const float y = (nt == 0 ? acc20[r] : acc21[r]) + b2c[nt] + hres;
                hn_out[n * 128 + colg] = y;
            }
        }
    }
}

extern "C" void kernel_launch(void* const* d_in, const int* in_sizes, int n_in,
                              void* d_out, int out_size, void* d_ws, size_t ws_size,
                              hipStream_t stream)
{
    const float* h     = (const float*)d_in[0];
    const float* pos   = (const float*)d_in[1];
    const int*   eidx  = (const int*)d_in[2];
    const float* eattr = (const float*)d_in[3];
    const float* eW1   = (const float*)d_in[4];
    const float* eb1   = (const float*)d_in[5];
    const float* eW2   = (const float*)d_in[6];
    const float* eb2   = (const float*)d_in[7];
    const float* aW    = (const float*)d_in[8];
    const float* ab    = (const float*)d_in[9];
    const float* nW1   = (const float*)d_in[10];
    const float* nb1   = (const float*)d_in[11];
    const float* nW2   = (const float*)d_in[12];
    const float* nb2   = (const float*)d_in[13];
    const float* pW2   = (const float*)d_in[14];

    float* out    = (float*)d_out;
    float* hn_out = out;                                   // N*128
    float* po_out = out + (size_t)NN * 128;                // N*3
    float* m_out  = po_out + (size_t)NN * 3;               // E*128

    // ws layout (bytes)
    char* wsb = (char*)d_ws;
    ushort_t* hbf       = (ushort_t*)(wsb + 0);            // 12,800,000
    ushort_t* agg_bf    = (ushort_t*)(wsb + 12800000);     // 12,800,000
    float*    trans     = (float*)   (wsb + 25600000);     //  7,680,000
    int*      deg       = (int*)     (wsb + 33280000);     //    200,000
    int*      row_ptr   = (int*)     (wsb + 33480192);     //    200,004
    int*      cursor    = (int*)     (wsb + 33680384);     //    200,000
    int*      edge_list = (int*)     (wsb + 33880576);     //  2,560,000

    hipMemsetAsync(deg, 0, sizeof(int) * NN, stream);

    prep_kernel<<<3200, 256, 0, stream>>>(h, hbf, eidx, deg);
    scan_kernel<<<1, 1024, 0, stream>>>(deg, row_ptr, cursor);
    scatter_kernel<<<(EE + 255) / 256, 256, 0, stream>>>(eidx, cursor, edge_list);

    egcl_edge_kernel<<<768, 256, 0, stream>>>(hbf, pos, eidx, eattr,
                                              eW1, eb1, eW2, eb2, aW, ab, pW2,
                                              m_out, trans);
    gather_agg_kernel<<<(NN * 64 + 255) / 256, 256, 0, stream>>>(
        m_out, trans, row_ptr, edge_list, pos, agg_bf, po_out);
    egcl_node_kernel<<<NN / 16, 256, 0, stream>>>(hbf, h, agg_bf,
                                                  nW1, nb1, nW2, nb2, hn_out);
}

// Round 8
// 699.212 us; speedup vs baseline: 1.3251x; 1.3251x over previous
//
#include <hip/hip_runtime.h>
#include <hip/hip_bf16.h>

#define NN 50000
#define EE 640000
#define FF 128
#define HH 128

typedef unsigned short ushort_t;
typedef unsigned int   uint_t;
using f32x4  = __attribute__((ext_vector_type(4))) float;
using bf16x8 = __attribute__((ext_vector_type(8))) __bf16;
using u16x8  = __attribute__((ext_vector_type(8))) unsigned short;

__device__ __forceinline__ ushort_t f2bf(float f) {
    union { float f; unsigned int i; } v; v.f = f;
    unsigned int r = v.i + 0x7fffu + ((v.i >> 16) & 1u);
    return (ushort_t)(r >> 16);
}
__device__ __forceinline__ float fsilu(float x) { return x / (1.f + __expf(-x)); }
__device__ __forceinline__ float fsig(float x)  { return 1.f / (1.f + __expf(-x)); }

__device__ __forceinline__ u16x8 cvt8(const float* p) {
    float4 a0 = *reinterpret_cast<const float4*>(p);
    float4 a1 = *reinterpret_cast<const float4*>(p + 4);
    u16x8 v;
    v[0] = f2bf(a0.x); v[1] = f2bf(a0.y); v[2] = f2bf(a0.z); v[3] = f2bf(a0.w);
    v[4] = f2bf(a1.x); v[5] = f2bf(a1.y); v[6] = f2bf(a1.z); v[7] = f2bf(a1.w);
    return v;
}

// ---------------------------------------------------------------------------
// prep: h f32->bf16  +  degree histogram (fused)
// ---------------------------------------------------------------------------
__global__ void prep_kernel(const float* __restrict__ h, ushort_t* __restrict__ hbf,
                            const int* __restrict__ eidx, int* __restrict__ deg)
{
    const int t = blockIdx.x * 256 + threadIdx.x;
    if (t * 8 < NN * 128) {
        u16x8 v = cvt8(h + (size_t)t * 8);
        *reinterpret_cast<u16x8*>(hbf + (size_t)t * 8) = v;
    }
    if (t < EE) atomicAdd(&deg[eidx[t]], 1);
}

__global__ void scan_kernel(const int* __restrict__ deg, int* __restrict__ row_ptr,
                            int* __restrict__ cursor)
{
    __shared__ int sdata[1024];
    const int t = threadIdx.x;
    const int chunk = (NN + 1023) / 1024;
    const int start = t * chunk;
    const int end   = min(start + chunk, NN);
    int s = 0;
    for (int i = start; i < end; ++i) s += deg[i];
    sdata[t] = s;
    __syncthreads();
    for (int off = 1; off < 1024; off <<= 1) {
        int v = (t >= off) ? sdata[t - off] : 0;
        __syncthreads();
        sdata[t] += v;
        __syncthreads();
    }
    int ox = sdata[t] - s;
    for (int i = start; i < end; ++i) {
        row_ptr[i] = ox; cursor[i] = ox; ox += deg[i];
    }
    if (t == 1023) row_ptr[NN] = sdata[1023];
}

__global__ void scatter_kernel(const int* __restrict__ eidx, int* __restrict__ cursor,
                               int* __restrict__ edge_list)
{
    const int e = blockIdx.x * 256 + threadIdx.x;
    if (e < EE) {
        const int r = eidx[e];
        const int p = atomicAdd(&cursor[r], 1);
        edge_list[p] = e;
    }
}

// ---------------------------------------------------------------------------
// Edge kernel: sequential 64-edge tiles, no atomics, 4 barriers.
// LDS = A(64 x 576B, XOR-swizzled first 512B) + M1(64 x 272B) = 54,272 B
//   -> 3 blocks/CU (with VGPR <= 170 at launch_bounds(256,2)).
// M2 aliases dead-A after layer1; PD in registers + shfl.
// ---------------------------------------------------------------------------
#define A_STR 288   // ushorts; 576 B row
#define M_STR 136   // ushorts; 272 B row

// swizzled pointer into A: row-local byte column b; first 512B swizzled
__device__ __forceinline__ ushort_t* a_ptr(ushort_t* base, int row, int b) {
    const int bs = (b < 512) ? (b ^ ((row & 7) << 4)) : b;
    return base + row * A_STR + (bs >> 1);
}

__global__ __launch_bounds__(256, 2) void egcl_edge_kernel(
    const ushort_t* __restrict__ hbf, const float* __restrict__ pos,
    const int* __restrict__ eidx, const float* __restrict__ eattr,
    const float* __restrict__ w1, const float* __restrict__ b1,
    const float* __restrict__ w2, const float* __restrict__ b2,
    const float* __restrict__ aW, const float* __restrict__ ab,
    const float* __restrict__ pW2,
    float* __restrict__ m_out, float* __restrict__ trans_out)
{
    __shared__ __align__(16) ushort_t A_sh[64 * A_STR];   // 36,864 B
    __shared__ __align__(16) ushort_t M1_sh[64 * M_STR];  // 17,408 B

    ushort_t* M2_sh = A_sh;                               // [64][136], dead-A alias

    const int tid  = threadIdx.x;
    const int lane = tid & 63;
    const int w    = tid >> 6;
    const int l15  = lane & 15;
    const int lg   = lane >> 4;

    // ---- weights in registers (per wave: cols 32w..32w+31) ----
    bf16x8 B1[9][2];
    bf16x8 B2[4][2];
    bf16x8 Bg[4];
    float b1c[2], b2c[2];
    const float abv = ab[0];
#pragma unroll
    for (int nt = 0; nt < 2; ++nt) {
        const int colg = 32 * w + 16 * nt + l15;
        b1c[nt] = b1[colg];
        b2c[nt] = b2[colg];
#pragma unroll
        for (int ks = 0; ks < 9; ++ks) {
            u16x8 v;
#pragma unroll
            for (int j = 0; j < 8; ++j) {
                const int k = 32 * ks + 8 * lg + j;
                v[j] = (k < 265) ? f2bf(w1[k * 128 + colg]) : (ushort_t)0;
            }
            B1[ks][nt] = __builtin_bit_cast(bf16x8, v);
        }
#pragma unroll
        for (int ks = 0; ks < 4; ++ks) {
            u16x8 v;
#pragma unroll
            for (int j = 0; j < 8; ++j) {
                const int k = 32 * ks + 8 * lg + j;
                v[j] = f2bf(w2[k * 128 + colg]);
            }
            B2[ks][nt] = __builtin_bit_cast(bf16x8, v);
        }
    }
#pragma unroll
    for (int ks = 0; ks < 4; ++ks) {
        u16x8 v;
#pragma unroll
        for (int j = 0; j < 8; ++j) {
            const int k = 32 * ks + 8 * lg + j;
            v[j] = (l15 == 0) ? f2bf(aW[k]) : (l15 == 1 ? f2bf(pW2[k]) : (ushort_t)0);
        }
        Bg[ks] = __builtin_bit_cast(bf16x8, v);
    }

    const int ei = tid >> 2;   // edge slot 0..63
    const int et = tid & 3;    // 4 threads/slot, 64B each per region

    for (int tile = blockIdx.x; tile < EE / 64; tile += gridDim.x) {
        // ---- stage (pd kept in registers on et==0 lanes) ----
        float pdx = 0.f, pdy = 0.f, pdz = 0.f;
        {
            const int e = tile * 64 + ei;
            const int r = eidx[e];
            const int c = eidx[EE + e];
            const ushort_t* hr = hbf + (size_t)r * 128 + et * 32;
            const ushort_t* hc = hbf + (size_t)c * 128 + et * 32;
#pragma unroll
            for (int q = 0; q < 4; ++q) {
                *reinterpret_cast<u16x8*>(a_ptr(A_sh, ei, 64 * et + 16 * q)) =
                    *reinterpret_cast<const u16x8*>(hr + q * 8);
                *reinterpret_cast<u16x8*>(a_ptr(A_sh, ei, 256 + 64 * et + 16 * q)) =
                    *reinterpret_cast<const u16x8*>(hc + q * 8);
            }
            if (et == 0) {
                pdx = pos[r * 3 + 0] - pos[c * 3 + 0];
                pdy = pos[r * 3 + 1] - pos[c * 3 + 1];
                pdz = pos[r * 3 + 2] - pos[c * 3 + 2];
                const float ds = pdx * pdx + pdy * pdy + pdz * pdz;
                const float4 ea0 = *reinterpret_cast<const float4*>(eattr + (size_t)e * 8);
                const float4 ea1 = *reinterpret_cast<const float4*>(eattr + (size_t)e * 8 + 4);
                u16x8 v0;
                v0[0] = f2bf(ds);
                v0[1] = f2bf(ea0.x); v0[2] = f2bf(ea0.y); v0[3] = f2bf(ea0.z);
                v0[4] = f2bf(ea0.w); v0[5] = f2bf(ea1.x); v0[6] = f2bf(ea1.y);
                v0[7] = f2bf(ea1.z);
                *reinterpret_cast<u16x8*>(a_ptr(A_sh, ei, 512)) = v0;
                u16x8 v1 = {0, 0, 0, 0, 0, 0, 0, 0};
                v1[0] = f2bf(ea1.w);
                *reinterpret_cast<u16x8*>(a_ptr(A_sh, ei, 528)) = v1;
                u16x8 z = {0, 0, 0, 0, 0, 0, 0, 0};
                *reinterpret_cast<u16x8*>(a_ptr(A_sh, ei, 544)) = z;
                *reinterpret_cast<u16x8*>(a_ptr(A_sh, ei, 560)) = z;
            }
        }
        __syncthreads();                       // B1: A ready

        // ---- layer 1 ----
#pragma unroll
        for (int s = 0; s < 4; ++s) {
            f32x4 a0 = {0.f, 0.f, 0.f, 0.f};
            f32x4 a1 = {0.f, 0.f, 0.f, 0.f};
#pragma unroll
            for (int ks = 0; ks < 9; ++ks) {
                bf16x8 a = *reinterpret_cast<const bf16x8*>(
                    a_ptr(A_sh, 16 * s + l15, 64 * ks + 16 * lg));
                a0 = __builtin_amdgcn_mfma_f32_16x16x32_bf16(a, B1[ks][0], a0, 0, 0, 0);
                a1 = __builtin_amdgcn_mfma_f32_16x16x32_bf16(a, B1[ks][1], a1, 0, 0, 0);
            }
#pragma unroll
            for (int nt = 0; nt < 2; ++nt) {
#pragma unroll
                for (int rr = 0; rr < 4; ++rr) {
                    const float x = (nt == 0 ? a0[rr] : a1[rr]) + b1c[nt];
                    const int edge = 16 * s + 4 * lg + rr;
                    const int colg = 32 * w + 16 * nt + l15;
                    M1_sh[edge * M_STR + colg] = f2bf(fsilu(x));
                }
            }
        }
        __syncthreads();                       // B2: M1 ready, A dead

        // ---- layer 2 (writes M2 alias in dead A region) ----
        float m2v[4][2][4];
#pragma unroll
        for (int s = 0; s < 4; ++s) {
            f32x4 a0 = {0.f, 0.f, 0.f, 0.f};
            f32x4 a1 = {0.f, 0.f, 0.f, 0.f};
#pragma unroll
            for (int ks = 0; ks < 4; ++ks) {
                bf16x8 a = *reinterpret_cast<const bf16x8*>(
                    &M1_sh[(16 * s + l15) * M_STR + ks * 32 + lg * 8]);
                a0 = __builtin_amdgcn_mfma_f32_16x16x32_bf16(a, B2[ks][0], a0, 0, 0, 0);
                a1 = __builtin_amdgcn_mfma_f32_16x16x32_bf16(a, B2[ks][1], a1, 0, 0, 0);
            }
#pragma unroll
            for (int nt = 0; nt < 2; ++nt) {
#pragma unroll
                for (int rr = 0; rr < 4; ++rr) {
                    const float x = (nt == 0 ? a0[rr] : a1[rr]) + b2c[nt];
                    const float sv = fsilu(x);
                    m2v[s][nt][rr] = sv;
                    const int edge = 16 * s + 4 * lg + rr;
                    const int colg = 32 * w + 16 * nt + l15;
                    M2_sh[edge * M_STR + colg] = f2bf(sv);
                }
            }
        }
        __syncthreads();                       // B3: M2 ready

        // ---- gate (all subtiles per wave) + trans write (own subtile) ----
        float gq[4][4];
#pragma unroll
        for (int s = 0; s < 4; ++s) {
            f32x4 ga = {0.f, 0.f, 0.f, 0.f};
#pragma unroll
            for (int ks = 0; ks < 4; ++ks) {
                bf16x8 a = *reinterpret_cast<const bf16x8*>(
                    &M2_sh[(16 * s + l15) * M_STR + ks * 32 + lg * 8]);
                ga = __builtin_amdgcn_mfma_f32_16x16x32_bf16(a, Bg[ks], ga, 0, 0, 0);
            }
#pragma unroll
            for (int rr = 0; rr < 4; ++rr) {
                const float sa = __shfl(ga[rr], lane & 48);
                gq[s][rr] = fsig(sa + abv);
                if (s == w) {
                    const float sp = __shfl(ga[rr], (lane & 48) + 1);
                    // PD of edge 16w+4lg+rr lives on lane 16lg+4rr (same wave)
                    const float px = __shfl(pdx, 16 * lg + 4 * rr);
                    const float py = __shfl(pdy, 16 * lg + 4 * rr);
                    const float pz = __shfl(pdz, 16 * lg + 4 * rr);
                    if (l15 == 0) {
                        const int edge = 16 * w + 4 * lg + rr;
                        const float t = gq[s][rr] * sp;
                        const size_t e = (size_t)tile * 64 + edge;
                        trans_out[e * 3 + 0] = px * t;
                        trans_out[e * 3 + 1] = py * t;
                        trans_out[e * 3 + 2] = pz * t;
                    }
                }
            }
        }

        // ---- gated m write (sequential rows) ----
#pragma unroll
        for (int s = 0; s < 4; ++s) {
#pragma unroll
            for (int nt = 0; nt < 2; ++nt) {
#pragma unroll
                for (int rr = 0; rr < 4; ++rr) {
                    const int edge = 16 * s + 4 * lg + rr;
                    const int colg = 32 * w + 16 * nt + l15;
                    const size_t e = (size_t)tile * 64 + edge;
                    m_out[e * 128 + colg] = m2v[s][nt][rr] * gq[s][rr];
                }
            }
        }
        __syncthreads();                       // B4: protect A/M2 for next tile
    }
}

// ---------------------------------------------------------------------------
// Gather-aggregate: one wave per node. agg (bf16) + pos update.
// ---------------------------------------------------------------------------
__global__ __launch_bounds__(256, 4) void gather_agg_kernel(
    const float* __restrict__ m, const float* __restrict__ trans,
    const int* __restrict__ row_ptr, const int* __restrict__ edge_list,
    const float* __restrict__ pos,
    ushort_t* __restrict__ agg_bf, float* __restrict__ pos_out)
{
    const int nid = (blockIdx.x * 256 + threadIdx.x) >> 6;
    if (nid >= NN) return;
    const int lane = threadIdx.x & 63;
    const int b  = row_ptr[nid];
    const int en = row_ptr[nid + 1];

    float a0 = 0.f, a1 = 0.f, tc = 0.f;
    int j = b;
    for (; j + 4 <= en; j += 4) {
        const int e0 = edge_list[j],     e1 = edge_list[j + 1];
        const int e2 = edge_list[j + 2], e3 = edge_list[j + 3];
        const float2 v0 = *reinterpret_cast<const float2*>(m + (size_t)e0 * 128 + 2 * lane);
        const float2 v1 = *reinterpret_cast<const float2*>(m + (size_t)e1 * 128 + 2 * lane);
        const float2 v2 = *reinterpret_cast<const float2*>(m + (size_t)e2 * 128 + 2 * lane);
        const float2 v3 = *reinterpret_cast<const float2*>(m + (size_t)e3 * 128 + 2 * lane);
        a0 += v0.x + v1.x + v2.x + v3.x;
        a1 += v0.y + v1.y + v2.y + v3.y;
        if (lane < 3)
            tc += trans[(size_t)e0 * 3 + lane] + trans[(size_t)e1 * 3 + lane]
                + trans[(size_t)e2 * 3 + lane] + trans[(size_t)e3 * 3 + lane];
    }
    for (; j < en; ++j) {
        const int e0 = edge_list[j];
        const float2 v0 = *reinterpret_cast<const float2*>(m + (size_t)e0 * 128 + 2 * lane);
        a0 += v0.x; a1 += v0.y;
        if (lane < 3) tc += trans[(size_t)e0 * 3 + lane];
    }

    const uint_t pk = (uint_t)f2bf(a0) | ((uint_t)f2bf(a1) << 16);
    reinterpret_cast<uint_t*>(agg_bf)[(size_t)nid * 64 + lane] = pk;
    if (lane < 3) {
        const float c = fmaxf((float)(en - b), 1.f);
        pos_out[(size_t)nid * 3 + lane] = pos[(size_t)nid * 3 + lane] + tc / c;
    }
}

// ---------------------------------------------------------------------------
// Node MLP: h_new = silu([hbf|agg_bf]@nW1+nb1)@nW2+nb2+h  (pure streaming)
// ---------------------------------------------------------------------------
__global__ __launch_bounds__(256, 4) void egcl_node_kernel(
    const ushort_t* __restrict__ hbf, const float* __restrict__ h,
    const ushort_t* __restrict__ agg_bf,
    const float* __restrict__ w1, const float* __restrict__ b1,
    const float* __restrict__ w2, const float* __restrict__ b2,
    float* __restrict__ hn_out)
{
    __shared__ __align__(16) ushort_t A_sh[16 * 264];
    __shared__ __align__(16) ushort_t M1_sh[16 * 136];

    const int tid  = threadIdx.x;
    const int lane = tid & 63;
    const int w    = tid >> 6;
    const int l15  = lane & 15;
    const int lg   = lane >> 4;

    bf16x8 B1[8][2];
    bf16x8 B2[4][2];
    float b1c[2], b2c[2];
#pragma unroll
    for (int nt = 0; nt < 2; ++nt) {
        const int colg = 32 * w + 16 * nt + l15;
        b1c[nt] = b1[colg];
        b2c[nt] = b2[colg];
#pragma unroll
        for (int ks = 0; ks < 8; ++ks) {
            u16x8 v;
#pragma unroll
            for (int j = 0; j < 8; ++j) {
                const int k = 32 * ks + 8 * lg + j;
                v[j] = f2bf(w1[k * 128 + colg]);
            }
            B1[ks][nt] = __builtin_bit_cast(bf16x8, v);
        }
#pragma unroll
        for (int ks = 0; ks < 4; ++ks) {
            u16x8 v;
#pragma unroll
            for (int j = 0; j < 8; ++j) {
                const int k = 32 * ks + 8 * lg + j;
                v[j] = f2bf(w2[k * 128 + colg]);
            }
            B2[ks][nt] = __builtin_bit_cast(bf16x8, v);
        }
    }

    const int ni = tid >> 4;
    const int nt16 = tid & 15;

    for (int tile = blockIdx.x; tile < NN / 16; tile += gridDim.x) {
        __syncthreads();
        const int base = tile * 16;
        {
            const size_t n = (size_t)base + ni;
            *reinterpret_cast<u16x8*>(&A_sh[ni * 264 + nt16 * 8]) =
                *reinterpret_cast<const u16x8*>(hbf + n * 128 + nt16 * 8);
            *reinterpret_cast<u16x8*>(&A_sh[ni * 264 + 128 + nt16 * 8]) =
                *reinterpret_cast<const u16x8*>(agg_bf + n * 128 + nt16 * 8);
        }
        __syncthreads();

        f32x4 acc10 = {0.f, 0.f, 0.f, 0.f};
        f32x4 acc11 = {0.f, 0.f, 0.f, 0.f};
#pragma unroll
        for (int ks = 0; ks < 8; ++ks) {
            bf16x8 a = *reinterpret_cast<const bf16x8*>(&A_sh[l15 * 264 + ks * 32 + lg * 8]);
            acc10 = __builtin_amdgcn_mfma_f32_16x16x32_bf16(a, B1[ks][0], acc10, 0, 0, 0);
            acc11 = __builtin_amdgcn_mfma_f32_16x16x32_bf16(a, B1[ks][1], acc11, 0, 0, 0);
        }
#pragma unroll
        for (int nt = 0; nt < 2; ++nt) {
#pragma unroll
            for (int r = 0; r < 4; ++r) {
                const float x = (nt == 0 ? acc10[r] : acc11[r]) + b1c[nt];
                const int nl = 4 * lg + r;
                const int colg = 32 * w + 16 * nt + l15;
                M1_sh[nl * 136 + colg] = f2bf(fsilu(x));
            }
        }
        __syncthreads();

        f32x4 acc20 = {0.f, 0.f, 0.f, 0.f};
        f32x4 acc21 = {0.f, 0.f, 0.f, 0.f};
#pragma unroll
        for (int ks = 0; ks < 4; ++ks) {
            bf16x8 a = *reinterpret_cast<const bf16x8*>(&M1_sh[l15 * 136 + ks * 32 + lg * 8]);
            acc20 = __builtin_amdgcn_mfma_f32_16x16x32_bf16(a, B2[ks][0], acc20, 0, 0, 0);
            acc21 = __builtin_amdgcn_mfma_f32_16x16x32_bf16(a, B2[ks][1], acc21, 0, 0, 0);
        }
#pragma unroll
        for (int nt = 0; nt < 2; ++nt) {
#pragma unroll
            for (int r = 0; r < 4; ++r) {
                const int nl = 4 * lg + r;
                const int colg = 32 * w + 16 * nt + l15;
                const size_t n = (size_t)base + nl;
                const float hres = h[n * 128 + colg];
                const float y = (nt == 0 ? acc20[r] : acc21[r]) + b2c[nt] + hres;
                hn_out[n * 128 + colg] = y;
            }
        }
    }
}

extern "C" void kernel_launch(void* const* d_in, const int* in_sizes, int n_in,
                              void* d_out, int out_size, void* d_ws, size_t ws_size,
                              hipStream_t stream)
{
    const float* h     = (const float*)d_in[0];
    const float* pos   = (const float*)d_in[1];
    const int*   eidx  = (const int*)d_in[2];
    const float* eattr = (const float*)d_in[3];
    const float* eW1   = (const float*)d_in[4];
    const float* eb1   = (const float*)d_in[5];
    const float* eW2   = (const float*)d_in[6];
    const float* eb2   = (const float*)d_in[7];
    const float* aW    = (const float*)d_in[8];
    const float* ab    = (const float*)d_in[9];
    const float* nW1   = (const float*)d_in[10];
    const float* nb1   = (const float*)d_in[11];
    const float* nW2   = (const float*)d_in[12];
    const float* nb2   = (const float*)d_in[13];
    const float* pW2   = (const float*)d_in[14];

    float* out    = (float*)d_out;
    float* hn_out = out;                                   // N*128
    float* po_out = out + (size_t)NN * 128;                // N*3
    float* m_out  = po_out + (size_t)NN * 3;               // E*128

    // ws layout (bytes)
    char* wsb = (char*)d_ws;
    ushort_t* hbf       = (ushort_t*)(wsb + 0);            // 12,800,000
    ushort_t* agg_bf    = (ushort_t*)(wsb + 12800000);     // 12,800,000
    float*    trans     = (float*)   (wsb + 25600000);     //  7,680,000
    int*      deg       = (int*)     (wsb + 33280000);     //    200,000
    int*      row_ptr   = (int*)     (wsb + 33480192);     //    200,004
    int*      cursor    = (int*)     (wsb + 33680384);     //    200,000
    int*      edge_list = (int*)     (wsb + 33880576);     //  2,560,000

    hipMemsetAsync(deg, 0, sizeof(int) * NN, stream);

    prep_kernel<<<3200, 256, 0, stream>>>(h, hbf, eidx, deg);
    scan_kernel<<<1, 1024, 0, stream>>>(deg, row_ptr, cursor);
    scatter_kernel<<<(EE + 255) / 256, 256, 0, stream>>>(eidx, cursor, edge_list);

    egcl_edge_kernel<<<768, 256, 0, stream>>>(hbf, pos, eidx, eattr,
                                              eW1, eb1, eW2, eb2, aW, ab, pW2,
                                              m_out, trans);
    gather_agg_kernel<<<(NN * 64 + 255) / 256, 256, 0, stream>>>(
        m_out, trans, row_ptr, edge_list, pos, agg_bf, po_out);
    egcl_node_kernel<<<NN / 16, 256, 0, stream>>>(hbf, h, agg_bf,
                                                  nW1, nb1, nW2, nb2, hn_out);
}

// Round 9
// 539.568 us; speedup vs baseline: 1.7171x; 1.2959x over previous
//
#include <hip/hip_runtime.h>
#include <hip/hip_bf16.h>

#define NN 50000
#define EE 640000
#define FF 128
#define HH 128

typedef unsigned short ushort_t;
typedef unsigned int   uint_t;
using f32x4  = __attribute__((ext_vector_type(4))) float;
using bf16x8 = __attribute__((ext_vector_type(8))) __bf16;
using u16x8  = __attribute__((ext_vector_type(8))) unsigned short;

__device__ __forceinline__ ushort_t f2bf(float f) {
    union { float f; unsigned int i; } v; v.f = f;
    unsigned int r = v.i + 0x7fffu + ((v.i >> 16) & 1u);
    return (ushort_t)(r >> 16);
}
__device__ __forceinline__ float bf2f(uint_t u) {
    union { uint_t i; float f; } v; v.i = u << 16; return v.f;
}
__device__ __forceinline__ float fsilu(float x) { return x / (1.f + __expf(-x)); }
__device__ __forceinline__ float fsig(float x)  { return 1.f / (1.f + __expf(-x)); }

__device__ __forceinline__ u16x8 cvt8(const float* p) {
    float4 a0 = *reinterpret_cast<const float4*>(p);
    float4 a1 = *reinterpret_cast<const float4*>(p + 4);
    u16x8 v;
    v[0] = f2bf(a0.x); v[1] = f2bf(a0.y); v[2] = f2bf(a0.z); v[3] = f2bf(a0.w);
    v[4] = f2bf(a1.x); v[5] = f2bf(a1.y); v[6] = f2bf(a1.z); v[7] = f2bf(a1.w);
    return v;
}

// ---------------------------------------------------------------------------
// prep: h f32->bf16  +  degree histogram (fused)
// ---------------------------------------------------------------------------
__global__ void prep_kernel(const float* __restrict__ h, ushort_t* __restrict__ hbf,
                            const int* __restrict__ eidx, int* __restrict__ deg)
{
    const int t = blockIdx.x * 256 + threadIdx.x;
    if (t * 8 < NN * 128) {
        u16x8 v = cvt8(h + (size_t)t * 8);
        *reinterpret_cast<u16x8*>(hbf + (size_t)t * 8) = v;
    }
    if (t < EE) atomicAdd(&deg[eidx[t]], 1);
}

__global__ void scan_kernel(const int* __restrict__ deg, int* __restrict__ row_ptr,
                            int* __restrict__ cursor)
{
    __shared__ int sdata[1024];
    const int t = threadIdx.x;
    const int chunk = (NN + 1023) / 1024;
    const int start = t * chunk;
    const int end   = min(start + chunk, NN);
    int s = 0;
    for (int i = start; i < end; ++i) s += deg[i];
    sdata[t] = s;
    __syncthreads();
    for (int off = 1; off < 1024; off <<= 1) {
        int v = (t >= off) ? sdata[t - off] : 0;
        __syncthreads();
        sdata[t] += v;
        __syncthreads();
    }
    int ox = sdata[t] - s;
    for (int i = start; i < end; ++i) {
        row_ptr[i] = ox; cursor[i] = ox; ox += deg[i];
    }
    if (t == 1023) row_ptr[NN] = sdata[1023];
}

__global__ void scatter_kernel(const int* __restrict__ eidx, int* __restrict__ cursor,
                               int* __restrict__ edge_list, int* __restrict__ row_sorted)
{
    const int e = blockIdx.x * 256 + threadIdx.x;
    if (e < EE) {
        const int r = eidx[e];
        const int p = atomicAdd(&cursor[r], 1);
        edge_list[p] = e;
        row_sorted[p] = r;
    }
}

// ---------------------------------------------------------------------------
// Edge kernel, CSR-ordered 64-edge tiles with in-kernel aggregation.
// LDS: A(64x288 swz) + M1(64x136) + ROW/EO/GATE = ~55KB -> 2 blocks/CU.
// M2 aliases dead-A. PD in staging-lane registers (+shfl). 5 barriers/tile.
// Wave w: MFMA cols 32w..32w+31 for layers; OWNS rows 16w..16w+15 for the
// gate + coalesced m_out write. Segmented LDS scan -> few f32 atomics.
// ---------------------------------------------------------------------------
#define A_STR 288   // ushorts
#define M_STR 136   // ushorts

__device__ __forceinline__ ushort_t* a_ptr(ushort_t* base, int row, int b) {
    const int bs = (b < 512) ? (b ^ ((row & 7) << 4)) : b;
    return base + row * A_STR + (bs >> 1);
}

__global__ __launch_bounds__(256, 2) void egcl_edge_kernel(
    const ushort_t* __restrict__ hbf, const float* __restrict__ pos,
    const int* __restrict__ eidx, const float* __restrict__ eattr,
    const int* __restrict__ edge_list, const int* __restrict__ row_sorted,
    const float* __restrict__ w1, const float* __restrict__ b1,
    const float* __restrict__ w2, const float* __restrict__ b2,
    const float* __restrict__ aW, const float* __restrict__ ab,
    const float* __restrict__ pW2,
    float* __restrict__ m_out, float* __restrict__ agg, float* __restrict__ agg_t)
{
    __shared__ __align__(16) ushort_t A_sh[64 * A_STR];   // 36,864 B
    __shared__ __align__(16) ushort_t M1_sh[64 * M_STR];  // 17,408 B
    __shared__ int   ROW_sh[64];
    __shared__ int   EO_sh[64];
    __shared__ float GATE_sh[64];

    ushort_t* M2_sh = A_sh;   // [64][M_STR] linear layout in dead-A region

    const int tid  = threadIdx.x;
    const int lane = tid & 63;
    const int w    = tid >> 6;
    const int l15  = lane & 15;
    const int lg   = lane >> 4;

    // ---- weights in registers (per wave: cols 32w..32w+31) ----
    bf16x8 B1[9][2];
    bf16x8 B2[4][2];
    bf16x8 Bg[4];
    float b1c[2], b2c[2];
    const float abv = ab[0];
#pragma unroll
    for (int nt = 0; nt < 2; ++nt) {
        const int colg = 32 * w + 16 * nt + l15;
        b1c[nt] = b1[colg];
        b2c[nt] = b2[colg];
#pragma unroll
        for (int ks = 0; ks < 9; ++ks) {
            u16x8 v;
#pragma unroll
            for (int j = 0; j < 8; ++j) {
                const int k = 32 * ks + 8 * lg + j;
                v[j] = (k < 265) ? f2bf(w1[k * 128 + colg]) : (ushort_t)0;
            }
            B1[ks][nt] = __builtin_bit_cast(bf16x8, v);
        }
#pragma unroll
        for (int ks = 0; ks < 4; ++ks) {
            u16x8 v;
#pragma unroll
            for (int j = 0; j < 8; ++j) {
                const int k = 32 * ks + 8 * lg + j;
                v[j] = f2bf(w2[k * 128 + colg]);
            }
            B2[ks][nt] = __builtin_bit_cast(bf16x8, v);
        }
    }
#pragma unroll
    for (int ks = 0; ks < 4; ++ks) {
        u16x8 v;
#pragma unroll
        for (int j = 0; j < 8; ++j) {
            const int k = 32 * ks + 8 * lg + j;
            v[j] = (l15 == 0) ? f2bf(aW[k]) : (l15 == 1 ? f2bf(pW2[k]) : (ushort_t)0);
        }
        Bg[ks] = __builtin_bit_cast(bf16x8, v);
    }

    const int ei = tid >> 2;   // CSR slot 0..63
    const int et = tid & 3;

    for (int tile = blockIdx.x; tile < EE / 64; tile += gridDim.x) {
        // ---- stage (CSR order; pd in regs on et==0 lanes) ----
        float pdx = 0.f, pdy = 0.f, pdz = 0.f;
        {
            const int p  = tile * 64 + ei;
            const int eo = edge_list[p];
            const int r  = row_sorted[p];
            const int c  = eidx[EE + eo];
            const ushort_t* hr = hbf + (size_t)r * 128 + et * 32;
            const ushort_t* hc = hbf + (size_t)c * 128 + et * 32;
#pragma unroll
            for (int q = 0; q < 4; ++q) {
                *reinterpret_cast<u16x8*>(a_ptr(A_sh, ei, 64 * et + 16 * q)) =
                    *reinterpret_cast<const u16x8*>(hr + q * 8);
                *reinterpret_cast<u16x8*>(a_ptr(A_sh, ei, 256 + 64 * et + 16 * q)) =
                    *reinterpret_cast<const u16x8*>(hc + q * 8);
            }
            if (et == 0) {
                ROW_sh[ei] = r;
                EO_sh[ei]  = eo;
                pdx = pos[r * 3 + 0] - pos[c * 3 + 0];
                pdy = pos[r * 3 + 1] - pos[c * 3 + 1];
                pdz = pos[r * 3 + 2] - pos[c * 3 + 2];
                const float ds = pdx * pdx + pdy * pdy + pdz * pdz;
                const float4 ea0 = *reinterpret_cast<const float4*>(eattr + (size_t)eo * 8);
                const float4 ea1 = *reinterpret_cast<const float4*>(eattr + (size_t)eo * 8 + 4);
                u16x8 v0;
                v0[0] = f2bf(ds);
                v0[1] = f2bf(ea0.x); v0[2] = f2bf(ea0.y); v0[3] = f2bf(ea0.z);
                v0[4] = f2bf(ea0.w); v0[5] = f2bf(ea1.x); v0[6] = f2bf(ea1.y);
                v0[7] = f2bf(ea1.z);
                *reinterpret_cast<u16x8*>(a_ptr(A_sh, ei, 512)) = v0;
                u16x8 v1 = {0, 0, 0, 0, 0, 0, 0, 0};
                v1[0] = f2bf(ea1.w);
                *reinterpret_cast<u16x8*>(a_ptr(A_sh, ei, 528)) = v1;
                u16x8 z = {0, 0, 0, 0, 0, 0, 0, 0};
                *reinterpret_cast<u16x8*>(a_ptr(A_sh, ei, 544)) = z;
                *reinterpret_cast<u16x8*>(a_ptr(A_sh, ei, 560)) = z;
            }
        }
        __syncthreads();                       // B1: A/ROW/EO ready

        // ---- layer 1 ----
#pragma unroll
        for (int s = 0; s < 4; ++s) {
            f32x4 a0 = {0.f, 0.f, 0.f, 0.f};
            f32x4 a1 = {0.f, 0.f, 0.f, 0.f};
#pragma unroll
            for (int ks = 0; ks < 9; ++ks) {
                bf16x8 a = *reinterpret_cast<const bf16x8*>(
                    a_ptr(A_sh, 16 * s + l15, 64 * ks + 16 * lg));
                a0 = __builtin_amdgcn_mfma_f32_16x16x32_bf16(a, B1[ks][0], a0, 0, 0, 0);
                a1 = __builtin_amdgcn_mfma_f32_16x16x32_bf16(a, B1[ks][1], a1, 0, 0, 0);
            }
#pragma unroll
            for (int nt = 0; nt < 2; ++nt) {
#pragma unroll
                for (int rr = 0; rr < 4; ++rr) {
                    const float x = (nt == 0 ? a0[rr] : a1[rr]) + b1c[nt];
                    const int edge = 16 * s + 4 * lg + rr;
                    const int colg = 32 * w + 16 * nt + l15;
                    M1_sh[edge * M_STR + colg] = f2bf(fsilu(x));
                }
            }
        }
        __syncthreads();                       // B2: M1 ready, A dead

        // ---- layer 2 -> M2 (bf16, dead-A alias) ----
#pragma unroll
        for (int s = 0; s < 4; ++s) {
            f32x4 a0 = {0.f, 0.f, 0.f, 0.f};
            f32x4 a1 = {0.f, 0.f, 0.f, 0.f};
#pragma unroll
            for (int ks = 0; ks < 4; ++ks) {
                bf16x8 a = *reinterpret_cast<const bf16x8*>(
                    &M1_sh[(16 * s + l15) * M_STR + ks * 32 + lg * 8]);
                a0 = __builtin_amdgcn_mfma_f32_16x16x32_bf16(a, B2[ks][0], a0, 0, 0, 0);
                a1 = __builtin_amdgcn_mfma_f32_16x16x32_bf16(a, B2[ks][1], a1, 0, 0, 0);
            }
#pragma unroll
            for (int nt = 0; nt < 2; ++nt) {
#pragma unroll
                for (int rr = 0; rr < 4; ++rr) {
                    const float x = (nt == 0 ? a0[rr] : a1[rr]) + b2c[nt];
                    const int edge = 16 * s + 4 * lg + rr;
                    const int colg = 32 * w + 16 * nt + l15;
                    M2_sh[edge * M_STR + colg] = f2bf(fsilu(x));
                }
            }
        }
        __syncthreads();                       // B3: M2 ready

        // ---- gate: own subtile only (4 MFMA) + GATE_sh + trans flush ----
        float gqw[4], txw[4], tyw[4], tzw[4];
        {
            f32x4 ga = {0.f, 0.f, 0.f, 0.f};
#pragma unroll
            for (int ks = 0; ks < 4; ++ks) {
                bf16x8 a = *reinterpret_cast<const bf16x8*>(
                    &M2_sh[(16 * w + l15) * M_STR + ks * 32 + lg * 8]);
                ga = __builtin_amdgcn_mfma_f32_16x16x32_bf16(a, Bg[ks], ga, 0, 0, 0);
            }
#pragma unroll
            for (int rr = 0; rr < 4; ++rr) {
                const float sa = __shfl(ga[rr], lane & 48);
                const float sp = __shfl(ga[rr], (lane & 48) + 1);
                gqw[rr] = fsig(sa + abv);
                const float t = gqw[rr] * sp;
                const float px = __shfl(pdx, 16 * lg + 4 * rr);
                const float py = __shfl(pdy, 16 * lg + 4 * rr);
                const float pz = __shfl(pdz, 16 * lg + 4 * rr);
                txw[rr] = px * t; tyw[rr] = py * t; tzw[rr] = pz * t;
                if (l15 == 0) GATE_sh[16 * w + 4 * lg + rr] = gqw[rr];
            }
            if (l15 == 0) {
                int cur = -1; float t0 = 0.f, t1 = 0.f, t2 = 0.f;
#pragma unroll
                for (int rr = 0; rr < 4; ++rr) {
                    const int rid = ROW_sh[16 * w + 4 * lg + rr];
                    if (rid != cur) {
                        if (cur >= 0) {
                            atomicAdd(&agg_t[cur * 3 + 0], t0);
                            atomicAdd(&agg_t[cur * 3 + 1], t1);
                            atomicAdd(&agg_t[cur * 3 + 2], t2);
                        }
                        cur = rid; t0 = t1 = t2 = 0.f;
                    }
                    t0 += txw[rr]; t1 += tyw[rr]; t2 += tzw[rr];
                }
                atomicAdd(&agg_t[cur * 3 + 0], t0);
                atomicAdd(&agg_t[cur * 3 + 1], t1);
                atomicAdd(&agg_t[cur * 3 + 2], t2);
            }
        }

        // ---- coalesced gated m_out write: wave w owns rows 16w..16w+15 ----
#pragma unroll
        for (int j = 0; j < 16; ++j) {
            const int row = 16 * w + j;
            const uint_t pv = *reinterpret_cast<const uint_t*>(&M2_sh[row * M_STR + 2 * lane]);
            const float g = __shfl(gqw[j & 3], 16 * (j >> 2));
            float2 st;
            st.x = bf2f(pv & 0xffffu) * g;
            st.y = bf2f(pv >> 16) * g;
            *reinterpret_cast<float2*>(&m_out[(size_t)EO_sh[row] * 128 + 2 * lane]) = st;
        }
        __syncthreads();                       // B4: GATE_sh visible for scan

        // ---- segmented column scan: agg[row] += gated m sums ----
        {
            const int col = tid & 127;
            const int j0  = (tid >> 7) * 32;
            int cur = ROW_sh[j0];
            float acc = 0.f;
#pragma unroll 4
            for (int j = j0; j < j0 + 32; ++j) {
                const int rid = ROW_sh[j];
                const float v = bf2f((uint_t)M2_sh[j * M_STR + col]) * GATE_sh[j];
                if (rid != cur) {
                    atomicAdd(&agg[(size_t)cur * 128 + col], acc);
                    acc = 0.f; cur = rid;
                }
                acc += v;
            }
            atomicAdd(&agg[(size_t)cur * 128 + col], acc);
        }
        __syncthreads();                       // B5: protect LDS for next tile
    }
}

// ---------------------------------------------------------------------------
// Node kernel: streaming. h_new = silu([hbf|bf16(agg)]@nW1+nb1)@nW2+nb2+h,
// pos_new = pos + agg_t / max(deg,1)  (deg from row_ptr diff)
// ---------------------------------------------------------------------------
__global__ __launch_bounds__(256, 4) void egcl_node_kernel(
    const ushort_t* __restrict__ hbf, const float* __restrict__ h,
    const float* __restrict__ agg, const float* __restrict__ agg_t,
    const int* __restrict__ row_ptr, const float* __restrict__ pos,
    const float* __restrict__ w1, const float* __restrict__ b1,
    const float* __restrict__ w2, const float* __restrict__ b2,
    float* __restrict__ hn_out, float* __restrict__ pos_out)
{
    __shared__ __align__(16) ushort_t A_sh[16 * 264];
    __shared__ __align__(16) ushort_t M1_sh[16 * 136];

    const int tid  = threadIdx.x;
    const int lane = tid & 63;
    const int w    = tid >> 6;
    const int l15  = lane & 15;
    const int lg   = lane >> 4;

    bf16x8 B1[8][2];
    bf16x8 B2[4][2];
    float b1c[2], b2c[2];
#pragma unroll
    for (int nt = 0; nt < 2; ++nt) {
        const int colg = 32 * w + 16 * nt + l15;
        b1c[nt] = b1[colg];
        b2c[nt] = b2[colg];
#pragma unroll
        for (int ks = 0; ks < 8; ++ks) {
            u16x8 v;
#pragma unroll
            for (int j = 0; j < 8; ++j) {
                const int k = 32 * ks + 8 * lg + j;
                v[j] = f2bf(w1[k * 128 + colg]);
            }
            B1[ks][nt] = __builtin_bit_cast(bf16x8, v);
        }
#pragma unroll
        for (int ks = 0; ks < 4; ++ks) {
            u16x8 v;
#pragma unroll
            for (int j = 0; j < 8; ++j) {
                const int k = 32 * ks + 8 * lg + j;
                v[j] = f2bf(w2[k * 128 + colg]);
            }
            B2[ks][nt] = __builtin_bit_cast(bf16x8, v);
        }
    }

    const int ni = tid >> 4;
    const int nt16 = tid & 15;

    for (int tile = blockIdx.x; tile < NN / 16; tile += gridDim.x) {
        __syncthreads();
        const int base = tile * 16;
        {
            const size_t n = (size_t)base + ni;
            *reinterpret_cast<u16x8*>(&A_sh[ni * 264 + nt16 * 8]) =
                *reinterpret_cast<const u16x8*>(hbf + n * 128 + nt16 * 8);
            u16x8 av = cvt8(agg + n * 128 + nt16 * 8);
            *reinterpret_cast<u16x8*>(&A_sh[ni * 264 + 128 + nt16 * 8]) = av;
        }
        if (tid < 48) {
            const int nl = tid / 3, d = tid % 3;
            const size_t n = (size_t)base + nl;
            const float c = (float)(row_ptr[n + 1] - row_ptr[n]);
            pos_out[n * 3 + d] = pos[n * 3 + d] + agg_t[n * 3 + d] / fmaxf(c, 1.f);
        }
        __syncthreads();

        f32x4 acc10 = {0.f, 0.f, 0.f, 0.f};
        f32x4 acc11 = {0.f, 0.f, 0.f, 0.f};
#pragma unroll
        for (int ks = 0; ks < 8; ++ks) {
            bf16x8 a = *reinterpret_cast<const bf16x8*>(&A_sh[l15 * 264 + ks * 32 + lg * 8]);
            acc10 = __builtin_amdgcn_mfma_f32_16x16x32_bf16(a, B1[ks][0], acc10, 0, 0, 0);
            acc11 = __builtin_amdgcn_mfma_f32_16x16x32_bf16(a, B1[ks][1], acc11, 0, 0, 0);
        }
#pragma unroll
        for (int nt = 0; nt < 2; ++nt) {
#pragma unroll
            for (int r = 0; r < 4; ++r) {
                const float x = (nt == 0 ? acc10[r] : acc11[r]) + b1c[nt];
                const int nl = 4 * lg + r;
                const int colg = 32 * w + 16 * nt + l15;
                M1_sh[nl * 136 + colg] = f2bf(fsilu(x));
            }
        }
        __syncthreads();

        f32x4 acc20 = {0.f, 0.f, 0.f, 0.f};
        f32x4 acc21 = {0.f, 0.f, 0.f, 0.f};
#pragma unroll
        for (int ks = 0; ks < 4; ++ks) {
            bf16x8 a = *reinterpret_cast<const bf16x8*>(&M1_sh[l15 * 136 + ks * 32 + lg * 8]);
            acc20 = __builtin_amdgcn_mfma_f32_16x16x32_bf16(a, B2[ks][0], acc20, 0, 0, 0);
            acc21 = __builtin_amdgcn_mfma_f32_16x16x32_bf16(a, B2[ks][1], acc21, 0, 0, 0);
        }
#pragma unroll
        for (int nt = 0; nt < 2; ++nt) {
#pragma unroll
            for (int r = 0; r < 4; ++r) {
                const int nl = 4 * lg + r;
                const int colg = 32 * w + 16 * nt + l15;
                const size_t n = (size_t)base + nl;
                const float hres = h[n * 128 + colg];
                const float y = (nt == 0 ? acc20[r] : acc21[r]) + b2c[nt] + hres;
                hn_out[n * 128 + colg] = y;
            }
        }
    }
}

extern "C" void kernel_launch(void* const* d_in, const int* in_sizes, int n_in,
                              void* d_out, int out_size, void* d_ws, size_t ws_size,
                              hipStream_t stream)
{
    const float* h     = (const float*)d_in[0];
    const float* pos   = (const float*)d_in[1];
    const int*   eidx  = (const int*)d_in[2];
    const float* eattr = (const float*)d_in[3];
    const float* eW1   = (const float*)d_in[4];
    const float* eb1   = (const float*)d_in[5];
    const float* eW2   = (const float*)d_in[6];
    const float* eb2   = (const float*)d_in[7];
    const float* aW    = (const float*)d_in[8];
    const float* ab    = (const float*)d_in[9];
    const float* nW1   = (const float*)d_in[10];
    const float* nb1   = (const float*)d_in[11];
    const float* nW2   = (const float*)d_in[12];
    const float* nb2   = (const float*)d_in[13];
    const float* pW2   = (const float*)d_in[14];

    float* out    = (float*)d_out;
    float* hn_out = out;                                   // N*128
    float* po_out = out + (size_t)NN * 128;                // N*3
    float* m_out  = po_out + (size_t)NN * 3;               // E*128

    // ws layout (bytes)
    char* wsb = (char*)d_ws;
    float* agg        = (float*)(wsb + 0);                 // 25,600,000
    float* agg_t      = (float*)(wsb + 25600000);          //    600,000
    int*   deg        = (int*)  (wsb + 26200000);          //    200,000
    int*   row_ptr    = (int*)  (wsb + 26400000);          //    200,004
    int*   cursor     = (int*)  (wsb + 26600256);          //    200,000
    int*   edge_list  = (int*)  (wsb + 26800256);          //  2,560,000
    int*   row_sorted = (int*)  (wsb + 29360256);          //  2,560,000
    ushort_t* hbf     = (ushort_t*)(wsb + 31920256);       // 12,800,000

    // zero agg + agg_t + deg (contiguous)
    hipMemsetAsync(wsb, 0, 26400000, stream);

    prep_kernel<<<3200, 256, 0, stream>>>(h, hbf, eidx, deg);
    scan_kernel<<<1, 1024, 0, stream>>>(deg, row_ptr, cursor);
    scatter_kernel<<<(EE + 255) / 256, 256, 0, stream>>>(eidx, cursor, edge_list, row_sorted);

    egcl_edge_kernel<<<512, 256, 0, stream>>>(hbf, pos, eidx, eattr,
                                              edge_list, row_sorted,
                                              eW1, eb1, eW2, eb2, aW, ab, pW2,
                                              m_out, agg, agg_t);
    egcl_node_kernel<<<1024, 256, 0, stream>>>(hbf, h, agg, agg_t, row_ptr, pos,
                                               nW1, nb1, nW2, nb2,
                                               hn_out, po_out);
}